// Round 4
// baseline (1674.556 us; speedup 1.0000x reference)
//
#include <hip/hip_runtime.h>
#include <hip/hip_bf16.h>

// Problem constants (fixed by setup_inputs): B=4, C=256, H=W=256, h=w=8,
// hh=ww=32, N=1024 patches/batch, scale = C^-0.5 = 1/16, gamma = 1e-5.
#define NPB 1024
#define EPS_LN 1e-6f

// ---------------------------------------------------------------------------
// K1: x1 = x + dwc3x3(x) + b  (written to d_out), plus per-pixel LN stats
// over C=256 (mean, rstd).  Barrier-free: one thread per pixel, block = one
// image row (256 px), grid = (256 rows, 4 batches); loops all channels with
// 9 guarded global loads each (L1/L2 serve the overlap). No LDS, no
// __syncthreads — no reuse-race surface at all.
// ---------------------------------------------------------------------------
__global__ __launch_bounds__(256) void k_dwc_ln(
        const float* __restrict__ x, const float* __restrict__ dwc_w,
        const float* __restrict__ dwc_b, float* __restrict__ x1,
        float* __restrict__ meanb, float* __restrict__ rstdb)
{
    const int b = blockIdx.y;
    const int y = blockIdx.x;        // image row, uniform per block
    const int xx = threadIdx.x;      // image column
    const float* xb = x + (((size_t)b * 256) << 16);
    float* x1b = x1 + (((size_t)b * 256) << 16);
    float s1 = 0.f, s2 = 0.f;
    for (int c = 0; c < 256; ++c) {
        const float* xc = xb + ((size_t)c << 16);
        const float* wp = dwc_w + c * 9;  // uniform scalar loads
        float acc = dwc_b[c];
        float cen = 0.f;
        #pragma unroll
        for (int dy = 0; dy < 3; ++dy) {
            int yy = y + dy - 1;
            if ((unsigned)yy >= 256u) continue;   // uniform branch (y uniform)
            const float* row = xc + (yy << 8);
            #pragma unroll
            for (int dx = 0; dx < 3; ++dx) {
                int x2 = xx + dx - 1;
                float v = ((unsigned)x2 < 256u) ? row[x2] : 0.f;
                acc += v * wp[dy * 3 + dx];
                if (dy == 1 && dx == 1) cen = v;
            }
        }
        float v1 = cen + acc;        // x + dwc(x) + b
        x1b[((size_t)c << 16) + (y << 8) + xx] = v1;
        s1 += v1; s2 += v1 * v1;
    }
    float mu = s1 * (1.f / 256.f);
    float var = s2 * (1.f / 256.f) - mu * mu;
    meanb[((size_t)b << 16) + (y << 8) + xx] = mu;
    rstdb[((size_t)b << 16) + (y << 8) + xx] = rsqrtf(var + EPS_LN);
}

// ---------------------------------------------------------------------------
// K2: stokens0[b][n][c] = mean over the 8x8 pixel block of LN(x1).
// Channel-last stoken layout [b][1024][256]. Block = one (b,c) plane.
// 8-lane group reduction via clamp-free xor butterfly.
// ---------------------------------------------------------------------------
__global__ __launch_bounds__(256) void k_stokens0(
        const float* __restrict__ x1, const float* __restrict__ meanb,
        const float* __restrict__ rstdb, const float* __restrict__ lnw,
        const float* __restrict__ lnb, float* __restrict__ stA)
{
    const int c = blockIdx.x, b = blockIdx.y;
    const int tx = threadIdx.x;  // pixel column 0..255
    const float w = lnw[c], bb = lnb[c];
    const float* xp = x1 + ((size_t)(b * 256 + c) << 16);
    const float* mp = meanb + ((size_t)b << 16);
    const float* rp = rstdb + ((size_t)b << 16);
    for (int i = 0; i < 32; ++i) {
        float acc = 0.f;
        for (int dy = 0; dy < 8; ++dy) {
            int y = i * 8 + dy;
            float v = xp[(y << 8) + tx];
            acc += (v - mp[(y << 8) + tx]) * rp[(y << 8) + tx] * w + bb;
        }
        acc += __shfl_xor(acc, 1);
        acc += __shfl_xor(acc, 2);
        acc += __shfl_xor(acc, 4);   // all lanes in each 8-group hold the sum
        if ((tx & 7) == 0) {
            int j = tx >> 3;
            stA[(((size_t)b * NPB + i * 32 + j) << 8) + c] = acc * (1.f / 64.f);
        }
    }
}

// ---------------------------------------------------------------------------
// K3/K4: per-patch affinity. One block per patch (4096 total).
//  - load pf (64px x 256ch of LN(x1)) into LDS as bf16
//  - load 3x3 stoken neighborhood (zero-padded; /asum if ITER==1)
//  - S = pf^T pat * 1/16 ; softmax over k=9 (incl. zero logits for OOB)
//  - ITER==1: store aff (bf16) to global
//  - asum partials + st = pf*aff scattered (fold adjoint) via atomicAdd
// ---------------------------------------------------------------------------
template <int ITER>
__global__ __launch_bounds__(256) void k_aff(
        const float* __restrict__ x1, const float* __restrict__ meanb,
        const float* __restrict__ rstdb, const float* __restrict__ lnw,
        const float* __restrict__ lnb, const float* __restrict__ stok_in,
        const float* __restrict__ asum_in, float* __restrict__ stok_out,
        float* __restrict__ asum_out, __hip_bfloat16* __restrict__ aff_out)
{
    __shared__ __hip_bfloat16 pf[256][66];  // [c][p], padded (bank-clean)
    __shared__ float pat[256][12];          // [c][k]
    __shared__ float sa[64][12];            // S then aff, [p][k]
    __shared__ float mu_s[64], rs_s[64];
    __shared__ float lnw_s[256], lnb_s[256];

    const int blk = blockIdx.x;
    const int b = blk >> 10, n = blk & 1023;
    const int pi = n >> 5, pj = n & 31;
    const int tid = threadIdx.x;

    lnw_s[tid] = lnw[tid];
    lnb_s[tid] = lnb[tid];
    if (tid < 64) {
        int py = tid >> 3, px = tid & 7;
        size_t off = ((size_t)b << 16) + ((pi * 8 + py) << 8) + pj * 8 + px;
        mu_s[tid] = meanb[off];
        rs_s[tid] = rstdb[off];
    }
    {   // patches: thread = c
        int c = tid;
        const float* sp = stok_in + (((size_t)b * NPB) << 8) + c;
        for (int k = 0; k < 9; ++k) {
            int ni = pi + k / 3 - 1, nj = pj + k % 3 - 1;
            float v = 0.f;
            if ((unsigned)ni < 32u && (unsigned)nj < 32u) {
                int nn = ni * 32 + nj;
                v = sp[(size_t)nn << 8];
                if (ITER == 1) v /= (asum_in[b * NPB + nn] + 1e-12f);
            }
            pat[c][k] = v;
        }
    }
    __syncthreads();
    {   // pf load: 4 channels x 64 pixels per iteration
        int c0 = tid >> 6, p = tid & 63;
        int py = p >> 3, px = p & 7;
        const float mu = mu_s[p], rs = rs_s[p];
        const size_t base = ((size_t)b * 256) << 16;
        const int goff = ((pi * 8 + py) << 8) + pj * 8 + px;
        for (int cb = 0; cb < 64; ++cb) {
            int c = cb * 4 + c0;
            float v = x1[base + ((size_t)c << 16) + goff];
            float xl = (v - mu) * rs * lnw_s[c] + lnb_s[c];
            pf[c][p] = __float2bfloat16(xl);
        }
    }
    __syncthreads();
    // S[p][k] = sum_c pf[c][p]*pat[c][k], scaled
    for (int o = tid; o < 576; o += 256) {
        int p = o / 9, k = o - (o / 9) * 9;
        float s = 0.f;
        for (int c = 0; c < 256; ++c)
            s += __bfloat162float(pf[c][p]) * pat[c][k];
        sa[p][k] = s * 0.0625f;
    }
    __syncthreads();
    if (tid < 64) {  // softmax over k
        int p = tid;
        float m = sa[p][0];
        for (int k = 1; k < 9; ++k) m = fmaxf(m, sa[p][k]);
        float e[9], sum = 0.f;
        for (int k = 0; k < 9; ++k) { e[k] = __expf(sa[p][k] - m); sum += e[k]; }
        float inv = 1.f / sum;
        for (int k = 0; k < 9; ++k) sa[p][k] = e[k] * inv;
    }
    __syncthreads();
    if (ITER == 1) {
        for (int o = tid; o < 576; o += 256)
            aff_out[(size_t)blk * 576 + o] = __float2bfloat16(sa[o / 9][o % 9]);
    }
    if (tid < 9) {  // asum fold-scatter
        float s = 0.f;
        for (int p = 0; p < 64; ++p) s += sa[p][tid];
        int ni = pi + tid / 3 - 1, nj = pj + tid % 3 - 1;
        if ((unsigned)ni < 32u && (unsigned)nj < 32u)
            atomicAdd(&asum_out[b * NPB + ni * 32 + nj], s);
    }
    {   // st[c][k] = sum_p pf[c][p]*aff[p][k]; fold-scatter
        int c = tid;
        float acc[9];
        for (int k = 0; k < 9; ++k) acc[k] = 0.f;
        for (int p = 0; p < 64; ++p) {
            float v = __bfloat162float(pf[c][p]);
            for (int k = 0; k < 9; ++k) acc[k] += v * sa[p][k];
        }
        for (int k = 0; k < 9; ++k) {
            int ni = pi + k / 3 - 1, nj = pj + k % 3 - 1;
            if ((unsigned)ni < 32u && (unsigned)nj < 32u)
                atomicAdd(&stok_out[(((size_t)b * NPB + ni * 32 + nj) << 8) + c], acc[k]);
        }
    }
}

// ---------------------------------------------------------------------------
// K5a/K5c: 1x1 conv on channel-last stokens; NORM fuses /(asum+1e-12).
// Block: 8 pixels x 256 outputs.
// ---------------------------------------------------------------------------
template <int NORM>
__global__ __launch_bounds__(256) void k_conv1x1(
        const float* __restrict__ in, const float* __restrict__ asum,
        const float* __restrict__ w, const float* __restrict__ bias,
        float* __restrict__ out)
{
    __shared__ float in_s[8][256];
    const int pix0 = blockIdx.x * 8;
    const int tid = threadIdx.x;
    for (int p = 0; p < 8; ++p) {
        int gp = pix0 + p;
        float v = in[((size_t)gp << 8) + tid];
        if (NORM) v /= (asum[gp] + 1e-12f);
        in_s[p][tid] = v;
    }
    __syncthreads();
    const int o = tid;
    float bb = bias[o];
    float acc[8];
    for (int p = 0; p < 8; ++p) acc[p] = bb;
    const float4* w4 = (const float4*)(w + (size_t)o * 256);
    for (int c4 = 0; c4 < 64; ++c4) {
        float4 wv = w4[c4];
        for (int p = 0; p < 8; ++p) {
            acc[p] += in_s[p][c4 * 4 + 0] * wv.x + in_s[p][c4 * 4 + 1] * wv.y
                    + in_s[p][c4 * 4 + 2] * wv.z + in_s[p][c4 * 4 + 3] * wv.w;
        }
    }
    for (int p = 0; p < 8; ++p)
        out[((size_t)(pix0 + p) << 8) + o] = acc[p];
}

// ---------------------------------------------------------------------------
// K5b: depthwise 5x5, pad 2, on channel-last [b][32][32][256].
// ---------------------------------------------------------------------------
__global__ __launch_bounds__(256) void k_dwc5(
        const float* __restrict__ in, const float* __restrict__ w,
        const float* __restrict__ bias, float* __restrict__ out)
{
    const int i = blockIdx.x, b = blockIdx.y;
    const int c = threadIdx.x;
    float wr[25];
    for (int t = 0; t < 25; ++t) wr[t] = w[c * 25 + t];
    const float bb = bias[c];
    const float* inb = in + (((size_t)b * NPB) << 8) + c;
    float* outb = out + (((size_t)b * NPB) << 8) + c;
    for (int j = 0; j < 32; ++j) {
        float acc = bb;
        for (int di = 0; di < 5; ++di) {
            int y = i + di - 2;
            if ((unsigned)y >= 32u) continue;
            for (int dj = 0; dj < 5; ++dj) {
                int xv = j + dj - 2;
                if ((unsigned)xv >= 32u) continue;
                acc += inb[(size_t)(y * 32 + xv) << 8] * wr[di * 5 + dj];
            }
        }
        outb[(size_t)(i * 32 + j) << 8] = acc;
    }
}

// ---------------------------------------------------------------------------
// K6: per patch: sp = unfold(st3); po[c][p] = sum_k sp[c][k]*aff[p][k];
// out = x1 + gamma*po  (in-place on d_out which holds x1).
// ---------------------------------------------------------------------------
__global__ __launch_bounds__(256) void k_final(
        const float* __restrict__ st3, const __hip_bfloat16* __restrict__ aff,
        const float* __restrict__ gamma, float* __restrict__ io)
{
    __shared__ float sp[256][12];
    __shared__ float af[64][12];
    const int blk = blockIdx.x;
    const int b = blk >> 10, n = blk & 1023;
    const int pi = n >> 5, pj = n & 31;
    const int tid = threadIdx.x;
    {
        int c = tid;
        const float* s0 = st3 + (((size_t)b * NPB) << 8) + c;
        for (int k = 0; k < 9; ++k) {
            int ni = pi + k / 3 - 1, nj = pj + k % 3 - 1;
            float v = 0.f;
            if ((unsigned)ni < 32u && (unsigned)nj < 32u)
                v = s0[(size_t)(ni * 32 + nj) << 8];
            sp[c][k] = v;
        }
    }
    for (int o = tid; o < 576; o += 256)
        af[o / 9][o % 9] = __bfloat162float(aff[(size_t)blk * 576 + o]);
    __syncthreads();
    const int c0 = tid >> 6, p = tid & 63;
    const int py = p >> 3, px = p & 7;
    float ar[9];
    for (int k = 0; k < 9; ++k) ar[k] = af[p][k];
    const size_t base = (((size_t)b * 256) << 16) + ((pi * 8 + py) << 8) + pj * 8 + px;
    for (int cb = 0; cb < 64; ++cb) {
        int c = cb * 4 + c0;
        float po = 0.f;
        for (int k = 0; k < 9; ++k) po += sp[c][k] * ar[k];
        size_t idx = base + ((size_t)c << 16);
        io[idx] = io[idx] + gamma[c] * po;
    }
}

// ---------------------------------------------------------------------------
extern "C" void kernel_launch(void* const* d_in, const int* in_sizes, int n_in,
                              void* d_out, int out_size, void* d_ws, size_t ws_size,
                              hipStream_t stream)
{
    (void)in_sizes; (void)n_in; (void)out_size; (void)ws_size;
    const float* x     = (const float*)d_in[0];
    const float* dwc_w = (const float*)d_in[1];
    const float* dwc_b = (const float*)d_in[2];
    const float* ln_w  = (const float*)d_in[3];
    const float* ln_b  = (const float*)d_in[4];
    const float* r1_w  = (const float*)d_in[5];
    const float* r1_b  = (const float*)d_in[6];
    const float* rd_w  = (const float*)d_in[7];
    const float* rd_b  = (const float*)d_in[8];
    const float* r2_w  = (const float*)d_in[9];
    const float* r2_b  = (const float*)d_in[10];
    const float* gamma = (const float*)d_in[11];
    float* out = (float*)d_out;
    float* ws  = (float*)d_ws;

    // ws layout (float offsets); total ~19.4 MiB
    float* stA   = ws;                    // 1,048,576 f
    float* stB   = ws + 1048576;          // 1,048,576 f (atomic target it0)
    float* stC   = ws + 2097152;          // 1,048,576 f (atomic target it1)
    float* asum0 = ws + 3145728;          // 4096 f
    float* asum1 = ws + 3149824;          // 4096 f
    float* meanb = ws + 3153920;          // 262,144 f
    float* rstdb = ws + 3416064;          // 262,144 f
    __hip_bfloat16* affb = (__hip_bfloat16*)(ws + 3678208);  // 2,359,296 bf16

    // zero the atomic-accumulated buffers (stB, stC, asum0, asum1 contiguous)
    hipMemsetAsync(stB, 0, (size_t)(2 * 1048576 + 2 * 4096) * sizeof(float), stream);

    k_dwc_ln<<<dim3(256, 4), 256, 0, stream>>>(x, dwc_w, dwc_b, out, meanb, rstdb);
    k_stokens0<<<dim3(256, 4), 256, 0, stream>>>(out, meanb, rstdb, ln_w, ln_b, stA);
    k_aff<0><<<4096, 256, 0, stream>>>(out, meanb, rstdb, ln_w, ln_b,
                                       stA, nullptr, stB, asum0, nullptr);
    k_aff<1><<<4096, 256, 0, stream>>>(out, meanb, rstdb, ln_w, ln_b,
                                       stB, asum0, stC, asum1, affb);
    k_conv1x1<1><<<512, 256, 0, stream>>>(stC, asum1, r1_w, r1_b, stA);
    k_dwc5<<<dim3(32, 4), 256, 0, stream>>>(stA, rd_w, rd_b, stB);
    k_conv1x1<0><<<512, 256, 0, stream>>>(stB, nullptr, r2_w, r2_b, stC);
    k_final<<<4096, 256, 0, stream>>>(stC, affb, gamma, out);
}

// Round 5
// 1443.626 us; speedup vs baseline: 1.1600x; 1.1600x over previous
//
#include <hip/hip_runtime.h>
#include <hip/hip_bf16.h>

// Problem constants (fixed by setup_inputs): B=4, C=256, H=W=256, h=w=8,
// hh=ww=32, N=1024 patches/batch, scale = C^-0.5 = 1/16, gamma = 1e-5.
#define NPB 1024
#define EPS_LN 1e-6f

// ---------------------------------------------------------------------------
// K1: x1 = x + dwc3x3(x) + b (to d_out) + partial LN stats.
// Vectorized: thread = 4 consecutive px (float4); wave = one 256-px row;
// block = 4 rows x 64 channels (cgroup); grid (64 rowgroups, 4 cgroups, 4 b).
// x-edge neighbors via wave shuffles (row == wave, so no cross-row leakage).
// Per-pixel partial sums (s1,s2) go to part1/part2[cg][b][y][x]; k_ln_fin
// reduces the 4 cgroups into mean/rstd. All fp32.
// ---------------------------------------------------------------------------
__global__ __launch_bounds__(256) void k_dwc_ln(
        const float* __restrict__ x, const float* __restrict__ dwc_w,
        const float* __restrict__ dwc_b, float* __restrict__ x1,
        float* __restrict__ part1, float* __restrict__ part2)
{
    const int b = blockIdx.z;
    const int cg = blockIdx.y;
    const int w = threadIdx.x >> 6;       // row within 4-row group
    const int lane = threadIdx.x & 63;
    const int y = blockIdx.x * 4 + w;     // wave-uniform image row
    const int x0 = lane << 2;             // first of 4 pixels
    const int c0 = cg * 64;
    const float* xb = x + (((size_t)(b * 256 + c0)) << 16);
    float* x1b = x1 + (((size_t)(b * 256 + c0)) << 16);
    const float4 z4 = {0.f, 0.f, 0.f, 0.f};
    float4 s1v = z4, s2v = z4;
    for (int ci = 0; ci < 64; ++ci) {
        const float* xc = xb + ((size_t)ci << 16);
        const float* wp = dwc_w + (size_t)(c0 + ci) * 9;  // uniform
        const float w00 = wp[0], w01 = wp[1], w02 = wp[2];
        const float w10 = wp[3], w11 = wp[4], w12 = wp[5];
        const float w20 = wp[6], w21 = wp[7], w22 = wp[8];
        const float bb = dwc_b[c0 + ci];
        float4 r0 = (y > 0)   ? *(const float4*)(xc + (((y - 1) << 8) + x0)) : z4;
        float4 r1 =             *(const float4*)(xc + ((y << 8) + x0));
        float4 r2 = (y < 255) ? *(const float4*)(xc + (((y + 1) << 8) + x0)) : z4;
        // x-edge neighbors from adjacent lanes (same wave = same row)
        float L0 = __shfl_up(r0.w, 1), L1 = __shfl_up(r1.w, 1), L2 = __shfl_up(r2.w, 1);
        float R0 = __shfl_down(r0.x, 1), R1 = __shfl_down(r1.x, 1), R2 = __shfl_down(r2.x, 1);
        if (lane == 0)  { L0 = 0.f; L1 = 0.f; L2 = 0.f; }   // x = -1 pad
        if (lane == 63) { R0 = 0.f; R1 = 0.f; R2 = 0.f; }   // x = 256 pad
        float4 acc;
        acc.x = bb + w00 * L0   + w01 * r0.x + w02 * r0.y
                   + w10 * L1   + w11 * r1.x + w12 * r1.y
                   + w20 * L2   + w21 * r2.x + w22 * r2.y;
        acc.y = bb + w00 * r0.x + w01 * r0.y + w02 * r0.z
                   + w10 * r1.x + w11 * r1.y + w12 * r1.z
                   + w20 * r2.x + w21 * r2.y + w22 * r2.z;
        acc.z = bb + w00 * r0.y + w01 * r0.z + w02 * r0.w
                   + w10 * r1.y + w11 * r1.z + w12 * r1.w
                   + w20 * r2.y + w21 * r2.z + w22 * r2.w;
        acc.w = bb + w00 * r0.z + w01 * r0.w + w02 * R0
                   + w10 * r1.z + w11 * r1.w + w12 * R1
                   + w20 * r2.z + w21 * r2.w + w22 * R2;
        float4 v1;
        v1.x = r1.x + acc.x; v1.y = r1.y + acc.y;
        v1.z = r1.z + acc.z; v1.w = r1.w + acc.w;
        *(float4*)(x1b + (((size_t)ci << 16) + (y << 8) + x0)) = v1;
        s1v.x += v1.x; s1v.y += v1.y; s1v.z += v1.z; s1v.w += v1.w;
        s2v.x += v1.x * v1.x; s2v.y += v1.y * v1.y;
        s2v.z += v1.z * v1.z; s2v.w += v1.w * v1.w;
    }
    const size_t po = (((size_t)(cg * 4 + b)) << 16) + (y << 8) + x0;
    *(float4*)(part1 + po) = s1v;
    *(float4*)(part2 + po) = s2v;
}

// ---------------------------------------------------------------------------
// K1b: reduce 4 cgroup partials -> per-pixel mean, rstd.
// ---------------------------------------------------------------------------
__global__ __launch_bounds__(256) void k_ln_fin(
        const float* __restrict__ part1, const float* __restrict__ part2,
        float* __restrict__ meanb, float* __restrict__ rstdb)
{
    const int b = blockIdx.y, y = blockIdx.x, xx = threadIdx.x;
    const int off = (y << 8) + xx;
    float s1 = 0.f, s2 = 0.f;
    #pragma unroll
    for (int cg = 0; cg < 4; ++cg) {
        size_t p = (((size_t)(cg * 4 + b)) << 16) + off;
        s1 += part1[p]; s2 += part2[p];
    }
    float mu = s1 * (1.f / 256.f);
    float var = s2 * (1.f / 256.f) - mu * mu;
    meanb[((size_t)b << 16) + off] = mu;
    rstdb[((size_t)b << 16) + off] = rsqrtf(var + EPS_LN);
}

// ---------------------------------------------------------------------------
// K2: stokens0[b][n][c] = mean over the 8x8 pixel block of LN(x1).
// Channel-last stoken layout [b][1024][256]. Block = one (b,c) plane.
// ---------------------------------------------------------------------------
__global__ __launch_bounds__(256) void k_stokens0(
        const float* __restrict__ x1, const float* __restrict__ meanb,
        const float* __restrict__ rstdb, const float* __restrict__ lnw,
        const float* __restrict__ lnb, float* __restrict__ stA)
{
    const int c = blockIdx.x, b = blockIdx.y;
    const int tx = threadIdx.x;  // pixel column 0..255
    const float w = lnw[c], bb = lnb[c];
    const float* xp = x1 + ((size_t)(b * 256 + c) << 16);
    const float* mp = meanb + ((size_t)b << 16);
    const float* rp = rstdb + ((size_t)b << 16);
    for (int i = 0; i < 32; ++i) {
        float acc = 0.f;
        for (int dy = 0; dy < 8; ++dy) {
            int y = i * 8 + dy;
            float v = xp[(y << 8) + tx];
            acc += (v - mp[(y << 8) + tx]) * rp[(y << 8) + tx] * w + bb;
        }
        acc += __shfl_xor(acc, 1);
        acc += __shfl_xor(acc, 2);
        acc += __shfl_xor(acc, 4);   // all lanes in each 8-group hold the sum
        if ((tx & 7) == 0) {
            int j = tx >> 3;
            stA[(((size_t)b * NPB + i * 32 + j) << 8) + c] = acc * (1.f / 64.f);
        }
    }
}

// ---------------------------------------------------------------------------
// K3/K4: per-patch affinity. One block per patch (4096 total).
// ---------------------------------------------------------------------------
template <int ITER>
__global__ __launch_bounds__(256) void k_aff(
        const float* __restrict__ x1, const float* __restrict__ meanb,
        const float* __restrict__ rstdb, const float* __restrict__ lnw,
        const float* __restrict__ lnb, const float* __restrict__ stok_in,
        const float* __restrict__ asum_in, float* __restrict__ stok_out,
        float* __restrict__ asum_out, __hip_bfloat16* __restrict__ aff_out)
{
    __shared__ __hip_bfloat16 pf[256][66];  // [c][p], padded (bank-clean)
    __shared__ float pat[256][12];          // [c][k]
    __shared__ float sa[64][12];            // S then aff, [p][k]
    __shared__ float mu_s[64], rs_s[64];
    __shared__ float lnw_s[256], lnb_s[256];

    const int blk = blockIdx.x;
    const int b = blk >> 10, n = blk & 1023;
    const int pi = n >> 5, pj = n & 31;
    const int tid = threadIdx.x;

    lnw_s[tid] = lnw[tid];
    lnb_s[tid] = lnb[tid];
    if (tid < 64) {
        int py = tid >> 3, px = tid & 7;
        size_t off = ((size_t)b << 16) + ((pi * 8 + py) << 8) + pj * 8 + px;
        mu_s[tid] = meanb[off];
        rs_s[tid] = rstdb[off];
    }
    {   // patches: thread = c
        int c = tid;
        const float* sp = stok_in + (((size_t)b * NPB) << 8) + c;
        for (int k = 0; k < 9; ++k) {
            int ni = pi + k / 3 - 1, nj = pj + k % 3 - 1;
            float v = 0.f;
            if ((unsigned)ni < 32u && (unsigned)nj < 32u) {
                int nn = ni * 32 + nj;
                v = sp[(size_t)nn << 8];
                if (ITER == 1) v /= (asum_in[b * NPB + nn] + 1e-12f);
            }
            pat[c][k] = v;
        }
    }
    __syncthreads();
    {   // pf load: 4 channels x 64 pixels per iteration
        int c0 = tid >> 6, p = tid & 63;
        int py = p >> 3, px = p & 7;
        const float mu = mu_s[p], rs = rs_s[p];
        const size_t base = ((size_t)b * 256) << 16;
        const int goff = ((pi * 8 + py) << 8) + pj * 8 + px;
        for (int cb = 0; cb < 64; ++cb) {
            int c = cb * 4 + c0;
            float v = x1[base + ((size_t)c << 16) + goff];
            float xl = (v - mu) * rs * lnw_s[c] + lnb_s[c];
            pf[c][p] = __float2bfloat16(xl);
        }
    }
    __syncthreads();
    // S[p][k] = sum_c pf[c][p]*pat[c][k], scaled
    for (int o = tid; o < 576; o += 256) {
        int p = o / 9, k = o - (o / 9) * 9;
        float s = 0.f;
        for (int c = 0; c < 256; ++c)
            s += __bfloat162float(pf[c][p]) * pat[c][k];
        sa[p][k] = s * 0.0625f;
    }
    __syncthreads();
    if (tid < 64) {  // softmax over k
        int p = tid;
        float m = sa[p][0];
        for (int k = 1; k < 9; ++k) m = fmaxf(m, sa[p][k]);
        float e[9], sum = 0.f;
        for (int k = 0; k < 9; ++k) { e[k] = __expf(sa[p][k] - m); sum += e[k]; }
        float inv = 1.f / sum;
        for (int k = 0; k < 9; ++k) sa[p][k] = e[k] * inv;
    }
    __syncthreads();
    if (ITER == 1) {
        for (int o = tid; o < 576; o += 256)
            aff_out[(size_t)blk * 576 + o] = __float2bfloat16(sa[o / 9][o % 9]);
    }
    if (tid < 9) {  // asum fold-scatter
        float s = 0.f;
        for (int p = 0; p < 64; ++p) s += sa[p][tid];
        int ni = pi + tid / 3 - 1, nj = pj + tid % 3 - 1;
        if ((unsigned)ni < 32u && (unsigned)nj < 32u)
            atomicAdd(&asum_out[b * NPB + ni * 32 + nj], s);
    }
    {   // st[c][k] = sum_p pf[c][p]*aff[p][k]; fold-scatter
        int c = tid;
        float acc[9];
        for (int k = 0; k < 9; ++k) acc[k] = 0.f;
        for (int p = 0; p < 64; ++p) {
            float v = __bfloat162float(pf[c][p]);
            for (int k = 0; k < 9; ++k) acc[k] += v * sa[p][k];
        }
        for (int k = 0; k < 9; ++k) {
            int ni = pi + k / 3 - 1, nj = pj + k % 3 - 1;
            if ((unsigned)ni < 32u && (unsigned)nj < 32u)
                atomicAdd(&stok_out[(((size_t)b * NPB + ni * 32 + nj) << 8) + c], acc[k]);
        }
    }
}

// ---------------------------------------------------------------------------
// K5a/K5c: 1x1 conv on channel-last stokens; NORM fuses /(asum+1e-12).
// ---------------------------------------------------------------------------
template <int NORM>
__global__ __launch_bounds__(256) void k_conv1x1(
        const float* __restrict__ in, const float* __restrict__ asum,
        const float* __restrict__ w, const float* __restrict__ bias,
        float* __restrict__ out)
{
    __shared__ float in_s[8][256];
    const int pix0 = blockIdx.x * 8;
    const int tid = threadIdx.x;
    for (int p = 0; p < 8; ++p) {
        int gp = pix0 + p;
        float v = in[((size_t)gp << 8) + tid];
        if (NORM) v /= (asum[gp] + 1e-12f);
        in_s[p][tid] = v;
    }
    __syncthreads();
    const int o = tid;
    float bb = bias[o];
    float acc[8];
    for (int p = 0; p < 8; ++p) acc[p] = bb;
    const float4* w4 = (const float4*)(w + (size_t)o * 256);
    for (int c4 = 0; c4 < 64; ++c4) {
        float4 wv = w4[c4];
        for (int p = 0; p < 8; ++p) {
            acc[p] += in_s[p][c4 * 4 + 0] * wv.x + in_s[p][c4 * 4 + 1] * wv.y
                    + in_s[p][c4 * 4 + 2] * wv.z + in_s[p][c4 * 4 + 3] * wv.w;
        }
    }
    for (int p = 0; p < 8; ++p)
        out[((size_t)(pix0 + p) << 8) + o] = acc[p];
}

// ---------------------------------------------------------------------------
// K5b: depthwise 5x5, pad 2, on channel-last [b][32][32][256].
// ---------------------------------------------------------------------------
__global__ __launch_bounds__(256) void k_dwc5(
        const float* __restrict__ in, const float* __restrict__ w,
        const float* __restrict__ bias, float* __restrict__ out)
{
    const int i = blockIdx.x, b = blockIdx.y;
    const int c = threadIdx.x;
    float wr[25];
    for (int t = 0; t < 25; ++t) wr[t] = w[c * 25 + t];
    const float bb = bias[c];
    const float* inb = in + (((size_t)b * NPB) << 8) + c;
    float* outb = out + (((size_t)b * NPB) << 8) + c;
    for (int j = 0; j < 32; ++j) {
        float acc = bb;
        for (int di = 0; di < 5; ++di) {
            int y = i + di - 2;
            if ((unsigned)y >= 32u) continue;
            for (int dj = 0; dj < 5; ++dj) {
                int xv = j + dj - 2;
                if ((unsigned)xv >= 32u) continue;
                acc += inb[(size_t)(y * 32 + xv) << 8] * wr[di * 5 + dj];
            }
        }
        outb[(size_t)(i * 32 + j) << 8] = acc;
    }
}

// ---------------------------------------------------------------------------
// K6: per patch: sp = unfold(st3); po[c][p] = sum_k sp[c][k]*aff[p][k];
// out = x1 + gamma*po (in-place RMW on d_out, float4-vectorized).
// Thread = (16-channel pass) x (4-px quad): cq = tid>>4, p4 = tid&15.
// ---------------------------------------------------------------------------
__global__ __launch_bounds__(256) void k_final(
        const float* __restrict__ st3, const __hip_bfloat16* __restrict__ aff,
        const float* __restrict__ gamma, float* __restrict__ io)
{
    __shared__ float sp[256][12];
    __shared__ float af[64][12];
    const int blk = blockIdx.x;
    const int b = blk >> 10, n = blk & 1023;
    const int pi = n >> 5, pj = n & 31;
    const int tid = threadIdx.x;
    {
        int c = tid;
        const float* s0 = st3 + (((size_t)b * NPB) << 8) + c;
        for (int k = 0; k < 9; ++k) {
            int ni = pi + k / 3 - 1, nj = pj + k % 3 - 1;
            float v = 0.f;
            if ((unsigned)ni < 32u && (unsigned)nj < 32u)
                v = s0[(size_t)(ni * 32 + nj) << 8];
            sp[c][k] = v;
        }
    }
    for (int o = tid; o < 576; o += 256)
        af[o / 9][o % 9] = __bfloat162float(aff[(size_t)blk * 576 + o]);
    __syncthreads();
    const int cq = tid >> 4;          // channel offset within each pass
    const int p4 = tid & 15;          // pixel quad: 4 consecutive px, same row
    const int py = p4 >> 1, px0 = (p4 & 1) * 4;
    float afr[4][9];
    #pragma unroll
    for (int j = 0; j < 4; ++j)
        #pragma unroll
        for (int k = 0; k < 9; ++k) afr[j][k] = af[p4 * 4 + j][k];
    const int gy = pi * 8 + py, gx = pj * 8 + px0;
    const size_t base = (((size_t)b * 256) << 16) + (gy << 8) + gx;
    for (int pass = 0; pass < 16; ++pass) {
        const int c = pass * 16 + cq;
        const float g = gamma[c];
        float s[9];
        #pragma unroll
        for (int k = 0; k < 9; ++k) s[k] = sp[c][k];
        float4 po = {0.f, 0.f, 0.f, 0.f};
        #pragma unroll
        for (int k = 0; k < 9; ++k) {
            po.x += s[k] * afr[0][k]; po.y += s[k] * afr[1][k];
            po.z += s[k] * afr[2][k]; po.w += s[k] * afr[3][k];
        }
        float4* ptr = (float4*)(io + base + ((size_t)c << 16));
        float4 v = *ptr;
        v.x += g * po.x; v.y += g * po.y; v.z += g * po.z; v.w += g * po.w;
        *ptr = v;
    }
}

// ---------------------------------------------------------------------------
extern "C" void kernel_launch(void* const* d_in, const int* in_sizes, int n_in,
                              void* d_out, int out_size, void* d_ws, size_t ws_size,
                              hipStream_t stream)
{
    (void)in_sizes; (void)n_in; (void)out_size; (void)ws_size;
    const float* x     = (const float*)d_in[0];
    const float* dwc_w = (const float*)d_in[1];
    const float* dwc_b = (const float*)d_in[2];
    const float* ln_w  = (const float*)d_in[3];
    const float* ln_b  = (const float*)d_in[4];
    const float* r1_w  = (const float*)d_in[5];
    const float* r1_b  = (const float*)d_in[6];
    const float* rd_w  = (const float*)d_in[7];
    const float* rd_b  = (const float*)d_in[8];
    const float* r2_w  = (const float*)d_in[9];
    const float* r2_b  = (const float*)d_in[10];
    const float* gamma = (const float*)d_in[11];
    float* out = (float*)d_out;
    float* ws  = (float*)d_ws;

    // ws layout (float offsets); total ~27.8 MiB
    float* stA   = ws;                    // 1,048,576 f
    float* stB   = ws + 1048576;          // 1,048,576 f (atomic target it0)
    float* stC   = ws + 2097152;          // 1,048,576 f (atomic target it1)
    float* asum0 = ws + 3145728;          // 4096 f
    float* asum1 = ws + 3149824;          // 4096 f
    float* meanb = ws + 3153920;          // 262,144 f
    float* rstdb = ws + 3416064;          // 262,144 f
    __hip_bfloat16* affb = (__hip_bfloat16*)(ws + 3678208);  // 2,359,296 bf16
    float* part1 = ws + 4857856;          // 1,048,576 f
    float* part2 = ws + 5906432;          // 1,048,576 f

    // zero the atomic-accumulated buffers (stB, stC, asum0, asum1 contiguous)
    hipMemsetAsync(stB, 0, (size_t)(2 * 1048576 + 2 * 4096) * sizeof(float), stream);

    k_dwc_ln<<<dim3(64, 4, 4), 256, 0, stream>>>(x, dwc_w, dwc_b, out, part1, part2);
    k_ln_fin<<<dim3(256, 4), 256, 0, stream>>>(part1, part2, meanb, rstdb);
    k_stokens0<<<dim3(256, 4), 256, 0, stream>>>(out, meanb, rstdb, ln_w, ln_b, stA);
    k_aff<0><<<4096, 256, 0, stream>>>(out, meanb, rstdb, ln_w, ln_b,
                                       stA, nullptr, stB, asum0, nullptr);
    k_aff<1><<<4096, 256, 0, stream>>>(out, meanb, rstdb, ln_w, ln_b,
                                       stB, asum0, stC, asum1, affb);
    k_conv1x1<1><<<512, 256, 0, stream>>>(stC, asum1, r1_w, r1_b, stA);
    k_dwc5<<<dim3(32, 4), 256, 0, stream>>>(stA, rd_w, rd_b, stB);
    k_conv1x1<0><<<512, 256, 0, stream>>>(stB, nullptr, r2_w, r2_b, stC);
    k_final<<<4096, 256, 0, stream>>>(stC, affb, gamma, out);
}

// Round 7
// 1225.155 us; speedup vs baseline: 1.3668x; 1.1783x over previous
//
#include <hip/hip_runtime.h>
#include <hip/hip_bf16.h>

// Problem constants (fixed by setup_inputs): B=4, C=256, H=W=256, h=w=8,
// hh=ww=32, N=1024 patches/batch, scale = C^-0.5 = 1/16, gamma = 1e-5.
#define NPB 1024
#define EPS_LN 1e-6f

// ---------------------------------------------------------------------------
// K1: x1 = x + dwc3x3(x) + b (to d_out) + partial LN stats.
// Vectorized: thread = 4 consecutive px (float4); wave = one 256-px row;
// block = 4 rows x 64 channels (cgroup); grid (64 rowgroups, 4 cgroups, 4 b).
// ---------------------------------------------------------------------------
__global__ __launch_bounds__(256) void k_dwc_ln(
        const float* __restrict__ x, const float* __restrict__ dwc_w,
        const float* __restrict__ dwc_b, float* __restrict__ x1,
        float* __restrict__ part1, float* __restrict__ part2)
{
    const int b = blockIdx.z;
    const int cg = blockIdx.y;
    const int w = threadIdx.x >> 6;       // row within 4-row group
    const int lane = threadIdx.x & 63;
    const int y = blockIdx.x * 4 + w;     // wave-uniform image row
    const int x0 = lane << 2;             // first of 4 pixels
    const int c0 = cg * 64;
    const float* xb = x + (((size_t)(b * 256 + c0)) << 16);
    float* x1b = x1 + (((size_t)(b * 256 + c0)) << 16);
    const float4 z4 = {0.f, 0.f, 0.f, 0.f};
    float4 s1v = z4, s2v = z4;
    for (int ci = 0; ci < 64; ++ci) {
        const float* xc = xb + ((size_t)ci << 16);
        const float* wp = dwc_w + (size_t)(c0 + ci) * 9;  // uniform
        const float w00 = wp[0], w01 = wp[1], w02 = wp[2];
        const float w10 = wp[3], w11 = wp[4], w12 = wp[5];
        const float w20 = wp[6], w21 = wp[7], w22 = wp[8];
        const float bb = dwc_b[c0 + ci];
        float4 r0 = (y > 0)   ? *(const float4*)(xc + (((y - 1) << 8) + x0)) : z4;
        float4 r1 =             *(const float4*)(xc + ((y << 8) + x0));
        float4 r2 = (y < 255) ? *(const float4*)(xc + (((y + 1) << 8) + x0)) : z4;
        float L0 = __shfl_up(r0.w, 1), L1 = __shfl_up(r1.w, 1), L2 = __shfl_up(r2.w, 1);
        float R0 = __shfl_down(r0.x, 1), R1 = __shfl_down(r1.x, 1), R2 = __shfl_down(r2.x, 1);
        if (lane == 0)  { L0 = 0.f; L1 = 0.f; L2 = 0.f; }
        if (lane == 63) { R0 = 0.f; R1 = 0.f; R2 = 0.f; }
        float4 acc;
        acc.x = bb + w00 * L0   + w01 * r0.x + w02 * r0.y
                   + w10 * L1   + w11 * r1.x + w12 * r1.y
                   + w20 * L2   + w21 * r2.x + w22 * r2.y;
        acc.y = bb + w00 * r0.x + w01 * r0.y + w02 * r0.z
                   + w10 * r1.x + w11 * r1.y + w12 * r1.z
                   + w20 * r2.x + w21 * r2.y + w22 * r2.z;
        acc.z = bb + w00 * r0.y + w01 * r0.z + w02 * r0.w
                   + w10 * r1.y + w11 * r1.z + w12 * r1.w
                   + w20 * r2.y + w21 * r2.z + w22 * r2.w;
        acc.w = bb + w00 * r0.z + w01 * r0.w + w02 * R0
                   + w10 * r1.z + w11 * r1.w + w12 * R1
                   + w20 * r2.z + w21 * r2.w + w22 * R2;
        float4 v1;
        v1.x = r1.x + acc.x; v1.y = r1.y + acc.y;
        v1.z = r1.z + acc.z; v1.w = r1.w + acc.w;
        *(float4*)(x1b + (((size_t)ci << 16) + (y << 8) + x0)) = v1;
        s1v.x += v1.x; s1v.y += v1.y; s1v.z += v1.z; s1v.w += v1.w;
        s2v.x += v1.x * v1.x; s2v.y += v1.y * v1.y;
        s2v.z += v1.z * v1.z; s2v.w += v1.w * v1.w;
    }
    const size_t po = (((size_t)(cg * 4 + b)) << 16) + (y << 8) + x0;
    *(float4*)(part1 + po) = s1v;
    *(float4*)(part2 + po) = s2v;
}

// ---------------------------------------------------------------------------
// K1b: reduce 4 cgroup partials -> per-pixel mean, rstd.
// ---------------------------------------------------------------------------
__global__ __launch_bounds__(256) void k_ln_fin(
        const float* __restrict__ part1, const float* __restrict__ part2,
        float* __restrict__ meanb, float* __restrict__ rstdb)
{
    const int b = blockIdx.y, y = blockIdx.x, xx = threadIdx.x;
    const int off = (y << 8) + xx;
    float s1 = 0.f, s2 = 0.f;
    #pragma unroll
    for (int cg = 0; cg < 4; ++cg) {
        size_t p = (((size_t)(cg * 4 + b)) << 16) + off;
        s1 += part1[p]; s2 += part2[p];
    }
    float mu = s1 * (1.f / 256.f);
    float var = s2 * (1.f / 256.f) - mu * mu;
    meanb[((size_t)b << 16) + off] = mu;
    rstdb[((size_t)b << 16) + off] = rsqrtf(var + EPS_LN);
}

// ---------------------------------------------------------------------------
// K2: stokens0[b][n][c] = mean over the 8x8 pixel block of LN(x1).
// ---------------------------------------------------------------------------
__global__ __launch_bounds__(256) void k_stokens0(
        const float* __restrict__ x1, const float* __restrict__ meanb,
        const float* __restrict__ rstdb, const float* __restrict__ lnw,
        const float* __restrict__ lnb, float* __restrict__ stA)
{
    const int c = blockIdx.x, b = blockIdx.y;
    const int tx = threadIdx.x;  // pixel column 0..255
    const float w = lnw[c], bb = lnb[c];
    const float* xp = x1 + ((size_t)(b * 256 + c) << 16);
    const float* mp = meanb + ((size_t)b << 16);
    const float* rp = rstdb + ((size_t)b << 16);
    for (int i = 0; i < 32; ++i) {
        float acc = 0.f;
        for (int dy = 0; dy < 8; ++dy) {
            int y = i * 8 + dy;
            float v = xp[(y << 8) + tx];
            acc += (v - mp[(y << 8) + tx]) * rp[(y << 8) + tx] * w + bb;
        }
        acc += __shfl_xor(acc, 1);
        acc += __shfl_xor(acc, 2);
        acc += __shfl_xor(acc, 4);
        if ((tx & 7) == 0) {
            int j = tx >> 3;
            stA[(((size_t)b * NPB + i * 32 + j) << 8) + c] = acc * (1.f / 64.f);
        }
    }
}

// ---------------------------------------------------------------------------
// K3/K4: per-patch affinity. One block per patch (4096 total).
// ---------------------------------------------------------------------------
template <int ITER>
__global__ __launch_bounds__(256) void k_aff(
        const float* __restrict__ x1, const float* __restrict__ meanb,
        const float* __restrict__ rstdb, const float* __restrict__ lnw,
        const float* __restrict__ lnb, const float* __restrict__ stok_in,
        const float* __restrict__ asum_in, float* __restrict__ stok_out,
        float* __restrict__ asum_out, __hip_bfloat16* __restrict__ aff_out)
{
    __shared__ __hip_bfloat16 pf[256][66];  // [c][p], padded (bank-clean)
    __shared__ float pat[256][12];          // [c][k]
    __shared__ float sa[64][12];            // S then aff, [p][k]
    __shared__ float mu_s[64], rs_s[64];
    __shared__ float lnw_s[256], lnb_s[256];

    const int blk = blockIdx.x;
    const int b = blk >> 10, n = blk & 1023;
    const int pi = n >> 5, pj = n & 31;
    const int tid = threadIdx.x;

    lnw_s[tid] = lnw[tid];
    lnb_s[tid] = lnb[tid];
    if (tid < 64) {
        int py = tid >> 3, px = tid & 7;
        size_t off = ((size_t)b << 16) + ((pi * 8 + py) << 8) + pj * 8 + px;
        mu_s[tid] = meanb[off];
        rs_s[tid] = rstdb[off];
    }
    {   // patches: thread = c
        int c = tid;
        const float* sp = stok_in + (((size_t)b * NPB) << 8) + c;
        for (int k = 0; k < 9; ++k) {
            int ni = pi + k / 3 - 1, nj = pj + k % 3 - 1;
            float v = 0.f;
            if ((unsigned)ni < 32u && (unsigned)nj < 32u) {
                int nn = ni * 32 + nj;
                v = sp[(size_t)nn << 8];
                if (ITER == 1) v /= (asum_in[b * NPB + nn] + 1e-12f);
            }
            pat[c][k] = v;
        }
    }
    __syncthreads();
    {   // pf load: 4 channels x 64 pixels per iteration
        int c0 = tid >> 6, p = tid & 63;
        int py = p >> 3, px = p & 7;
        const float mu = mu_s[p], rs = rs_s[p];
        const size_t base = ((size_t)b * 256) << 16;
        const int goff = ((pi * 8 + py) << 8) + pj * 8 + px;
        for (int cb = 0; cb < 64; ++cb) {
            int c = cb * 4 + c0;
            float v = x1[base + ((size_t)c << 16) + goff];
            float xl = (v - mu) * rs * lnw_s[c] + lnb_s[c];
            pf[c][p] = __float2bfloat16(xl);
        }
    }
    __syncthreads();
    // S[p][k] = sum_c pf[c][p]*pat[c][k], scaled
    for (int o = tid; o < 576; o += 256) {
        int p = o / 9, k = o - (o / 9) * 9;
        float s = 0.f;
        for (int c = 0; c < 256; ++c)
            s += __bfloat162float(pf[c][p]) * pat[c][k];
        sa[p][k] = s * 0.0625f;
    }
    __syncthreads();
    if (tid < 64) {  // softmax over k
        int p = tid;
        float m = sa[p][0];
        for (int k = 1; k < 9; ++k) m = fmaxf(m, sa[p][k]);
        float e[9], sum = 0.f;
        for (int k = 0; k < 9; ++k) { e[k] = __expf(sa[p][k] - m); sum += e[k]; }
        float inv = 1.f / sum;
        for (int k = 0; k < 9; ++k) sa[p][k] = e[k] * inv;
    }
    __syncthreads();
    if (ITER == 1) {
        for (int o = tid; o < 576; o += 256)
            aff_out[(size_t)blk * 576 + o] = __float2bfloat16(sa[o / 9][o % 9]);
    }
    if (tid < 9) {  // asum fold-scatter
        float s = 0.f;
        for (int p = 0; p < 64; ++p) s += sa[p][tid];
        int ni = pi + tid / 3 - 1, nj = pj + tid % 3 - 1;
        if ((unsigned)ni < 32u && (unsigned)nj < 32u)
            atomicAdd(&asum_out[b * NPB + ni * 32 + nj], s);
    }
    {   // st[c][k] = sum_p pf[c][p]*aff[p][k]; fold-scatter
        int c = tid;
        float acc[9];
        for (int k = 0; k < 9; ++k) acc[k] = 0.f;
        for (int p = 0; p < 64; ++p) {
            float v = __bfloat162float(pf[c][p]);
            for (int k = 0; k < 9; ++k) acc[k] += v * sa[p][k];
        }
        for (int k = 0; k < 9; ++k) {
            int ni = pi + k / 3 - 1, nj = pj + k % 3 - 1;
            if ((unsigned)ni < 32u && (unsigned)nj < 32u)
                atomicAdd(&stok_out[(((size_t)b * NPB + ni * 32 + nj) << 8) + c], acc[k]);
        }
    }
}

// ---------------------------------------------------------------------------
// K5a/K5c: 1x1 conv on channel-last stokens; NORM fuses /(asum+1e-12).
// ---------------------------------------------------------------------------
template <int NORM>
__global__ __launch_bounds__(256) void k_conv1x1(
        const float* __restrict__ in, const float* __restrict__ asum,
        const float* __restrict__ w, const float* __restrict__ bias,
        float* __restrict__ out)
{
    __shared__ float in_s[8][256];
    const int pix0 = blockIdx.x * 8;
    const int tid = threadIdx.x;
    for (int p = 0; p < 8; ++p) {
        int gp = pix0 + p;
        float v = in[((size_t)gp << 8) + tid];
        if (NORM) v /= (asum[gp] + 1e-12f);
        in_s[p][tid] = v;
    }
    __syncthreads();
    const int o = tid;
    float bb = bias[o];
    float acc[8];
    for (int p = 0; p < 8; ++p) acc[p] = bb;
    const float4* w4 = (const float4*)(w + (size_t)o * 256);
    for (int c4 = 0; c4 < 64; ++c4) {
        float4 wv = w4[c4];
        for (int p = 0; p < 8; ++p) {
            acc[p] += in_s[p][c4 * 4 + 0] * wv.x + in_s[p][c4 * 4 + 1] * wv.y
                    + in_s[p][c4 * 4 + 2] * wv.z + in_s[p][c4 * 4 + 3] * wv.w;
        }
    }
    for (int p = 0; p < 8; ++p)
        out[((size_t)(pix0 + p) << 8) + o] = acc[p];
}

// ---------------------------------------------------------------------------
// K5b: depthwise 5x5, pad 2, on channel-last [b][32][32][256].
// ---------------------------------------------------------------------------
__global__ __launch_bounds__(256) void k_dwc5(
        const float* __restrict__ in, const float* __restrict__ w,
        const float* __restrict__ bias, float* __restrict__ out)
{
    const int i = blockIdx.x, b = blockIdx.y;
    const int c = threadIdx.x;
    float wr[25];
    for (int t = 0; t < 25; ++t) wr[t] = w[c * 25 + t];
    const float bb = bias[c];
    const float* inb = in + (((size_t)b * NPB) << 8) + c;
    float* outb = out + (((size_t)b * NPB) << 8) + c;
    for (int j = 0; j < 32; ++j) {
        float acc = bb;
        for (int di = 0; di < 5; ++di) {
            int y = i + di - 2;
            if ((unsigned)y >= 32u) continue;
            for (int dj = 0; dj < 5; ++dj) {
                int xv = j + dj - 2;
                if ((unsigned)xv >= 32u) continue;
                acc += inb[(size_t)(y * 32 + xv) << 8] * wr[di * 5 + dj];
            }
        }
        outb[(size_t)(i * 32 + j) << 8] = acc;
    }
}

// ---------------------------------------------------------------------------
// K6 v2: row-strip layout. Block = (pi, cgroup of 64 ch, b), 512 threads.
// Wave = one full 256-px image row (thread = float4 quad) -> io RMW is a
// fully-coalesced 1KB wave transaction. 3x32 stoken neighborhood for the
// strip's 64 channels staged in LDS [3][34][66] (zero-padded cols/rows;
// stride 66 => 2-way/broadcast LDS reads, conflict-free). Each thread keeps
// its 36 aff weights in registers across the 64-channel loop.
// ---------------------------------------------------------------------------
__global__ __launch_bounds__(512) void k_final(
        const float* __restrict__ st3, const __hip_bfloat16* __restrict__ aff,
        const float* __restrict__ gamma, float* __restrict__ io)
{
    __shared__ float sp_s[3][34][66];     // [r][j'=col+1][c], 26.9 KB
    const int pi = blockIdx.x;
    const int cg = blockIdx.y;
    const int b  = blockIdx.z;
    const int c0 = cg * 64;
    const int tid = threadIdx.x;

    // stage: 3 stoken rows x 34 padded cols x 64 ch, coalesced over c
    for (int t = tid; t < 3 * 34 * 64; t += 512) {
        const int c  = t & 63;
        const int rj = t >> 6;            // 0..101
        const int jj = rj % 34;           // padded col index
        const int r  = rj / 34;           // 0..2
        const int nc = jj - 1;            // real stoken col
        const int nr = pi - 1 + r;        // real stoken row
        float v = 0.f;
        if ((unsigned)nr < 32u && (unsigned)nc < 32u)
            v = st3[(((size_t)(b * NPB + nr * 32 + nc)) << 8) + c0 + c];
        sp_s[r][jj][c] = v;
    }

    // per-thread aff weights (4 consecutive px of one patch row)
    const int y    = tid >> 6;            // row within strip, 0..7
    const int lane = tid & 63;
    const int x0   = lane << 2;           // image col of quad
    const int pj   = x0 >> 3;             // patch col
    const int p0   = y * 8 + (x0 & 7);    // first p index within patch
    const __hip_bfloat16* ab =
        aff + ((size_t)(b * NPB + pi * 32 + pj)) * 576 + p0 * 9;
    float afr[4][9];
    #pragma unroll
    for (int j = 0; j < 4; ++j)
        #pragma unroll
        for (int k = 0; k < 9; ++k)
            afr[j][k] = __bfloat162float(ab[j * 9 + k]);

    __syncthreads();

    const size_t iobase = (((size_t)(b * 256 + c0)) << 16)
                        + ((pi * 8 + y) << 8) + x0;
    #pragma unroll 2
    for (int ci = 0; ci < 64; ++ci) {
        const float g = gamma[c0 + ci];
        float spv[9];
        #pragma unroll
        for (int kr = 0; kr < 3; ++kr)
            #pragma unroll
            for (int kc = 0; kc < 3; ++kc)
                spv[kr * 3 + kc] = sp_s[kr][pj + kc][ci];
        float4 po = {0.f, 0.f, 0.f, 0.f};
        #pragma unroll
        for (int k = 0; k < 9; ++k) {
            po.x += spv[k] * afr[0][k]; po.y += spv[k] * afr[1][k];
            po.z += spv[k] * afr[2][k]; po.w += spv[k] * afr[3][k];
        }
        float4* ptr = (float4*)(io + iobase + ((size_t)ci << 16));
        float4 v = *ptr;
        v.x += g * po.x; v.y += g * po.y; v.z += g * po.z; v.w += g * po.w;
        *ptr = v;
    }
}

// ---------------------------------------------------------------------------
extern "C" void kernel_launch(void* const* d_in, const int* in_sizes, int n_in,
                              void* d_out, int out_size, void* d_ws, size_t ws_size,
                              hipStream_t stream)
{
    (void)in_sizes; (void)n_in; (void)out_size; (void)ws_size;
    const float* x     = (const float*)d_in[0];
    const float* dwc_w = (const float*)d_in[1];
    const float* dwc_b = (const float*)d_in[2];
    const float* ln_w  = (const float*)d_in[3];
    const float* ln_b  = (const float*)d_in[4];
    const float* r1_w  = (const float*)d_in[5];
    const float* r1_b  = (const float*)d_in[6];
    const float* rd_w  = (const float*)d_in[7];
    const float* rd_b  = (const float*)d_in[8];
    const float* r2_w  = (const float*)d_in[9];
    const float* r2_b  = (const float*)d_in[10];
    const float* gamma = (const float*)d_in[11];
    float* out = (float*)d_out;
    float* ws  = (float*)d_ws;

    // ws layout (float offsets); total ~27.8 MiB
    float* stA   = ws;                    // 1,048,576 f
    float* stB   = ws + 1048576;          // 1,048,576 f (atomic target it0)
    float* stC   = ws + 2097152;          // 1,048,576 f (atomic target it1)
    float* asum0 = ws + 3145728;          // 4096 f
    float* asum1 = ws + 3149824;          // 4096 f
    float* meanb = ws + 3153920;          // 262,144 f
    float* rstdb = ws + 3416064;          // 262,144 f
    __hip_bfloat16* affb = (__hip_bfloat16*)(ws + 3678208);  // 2,359,296 bf16
    float* part1 = ws + 4857856;          // 1,048,576 f
    float* part2 = ws + 5906432;          // 1,048,576 f

    // zero the atomic-accumulated buffers (stB, stC, asum0, asum1 contiguous)
    hipMemsetAsync(stB, 0, (size_t)(2 * 1048576 + 2 * 4096) * sizeof(float), stream);

    k_dwc_ln<<<dim3(64, 4, 4), 256, 0, stream>>>(x, dwc_w, dwc_b, out, part1, part2);
    k_ln_fin<<<dim3(256, 4), 256, 0, stream>>>(part1, part2, meanb, rstdb);
    k_stokens0<<<dim3(256, 4), 256, 0, stream>>>(out, meanb, rstdb, ln_w, ln_b, stA);
    k_aff<0><<<4096, 256, 0, stream>>>(out, meanb, rstdb, ln_w, ln_b,
                                       stA, nullptr, stB, asum0, nullptr);
    k_aff<1><<<4096, 256, 0, stream>>>(out, meanb, rstdb, ln_w, ln_b,
                                       stB, asum0, stC, asum1, affb);
    k_conv1x1<1><<<512, 256, 0, stream>>>(stC, asum1, r1_w, r1_b, stA);
    k_dwc5<<<dim3(32, 4), 256, 0, stream>>>(stA, rd_w, rd_b, stB);
    k_conv1x1<0><<<512, 256, 0, stream>>>(stB, nullptr, r2_w, r2_b, stC);
    k_final<<<dim3(32, 4, 4), 512, 0, stream>>>(stC, affb, gamma, out);
}